// Round 9
// baseline (346.872 us; speedup 1.0000x reference)
//
#include <hip/hip_runtime.h>
#include <hip/hip_bf16.h>

#define DIMC 384          // C
#define LL 785            // 1 + 28*28
#define FDIM 1536         // 4*C  (GEMM K)
#define ODIM 768          // 2*C  (GEMM N)
#define NPATCH 196        // 14*14
#define MROWS 12544       // B*196 (GEMM M)
#define BATCH 64

typedef __attribute__((ext_vector_type(8))) short bf16x8;
typedef __attribute__((ext_vector_type(4))) float floatx4;
typedef __attribute__((ext_vector_type(4))) unsigned short ushort4v;

// ws layout (bytes):
//   xbf   u16[50176*384]  @ 0           (38,535,168 B)  bf16(raw x feature rows)
//   wbf   u16[768*1536]   @ 38535168    ( 2,359,296 B)  bf16(gamma * w_red)
//   pst   f32x2[50176]    @ 40894464    (   401,408 B)  per-(b,l) partial (s,s2)
//   bias2 f32x2[768]      @ 41295872    (     6,144 B)  (gsum, bias) per o
//   flags int[65]         @ 41302016    (flags[0]=wall, flags[1+b]=vcnt[b])
#define WS_WBF_OFF  38535168
#define WS_PST_OFF  40894464
#define WS_B2_OFF   41295872
#define WS_FLAG_OFF 41302016

// Single fused kernel; roles by blockIdx (producers first in dispatch order):
#define RB_WBF   0       // [0,1152)     wbf             -> wall++
#define RB_BIAS  1152    // [1152,1344)  bias2           -> wall++
#define RB_CAST  1344    // [1344,2912)  cast+pstat      -> vcnt[b] += n
#define RB_CLS   2912    // [2912,3104)  cls             (independent)
#define RB_GEMM  3104    // [3104,3692)  gemm            (waits on flags)
#define TOTAL_BLOCKS 3692
#define WALL_TARGET 1344

__device__ __forceinline__ unsigned short f2bf(float f) {
  union { float f; unsigned int u; } v; v.f = f;
  unsigned int u = v.u + 0x7fffu + ((v.u >> 16) & 1u);   // RNE
  return (unsigned short)(u >> 16);
}

__device__ __forceinline__ void gload_lds16(const void* g, void* l) {
  __builtin_amdgcn_global_load_lds(
      (const __attribute__((address_space(1))) unsigned int*)g,
      (__attribute__((address_space(3))) unsigned int*)l, 16, 0, 0);
}

__device__ __forceinline__ int flag_peek(volatile int* p) {
  return __hip_atomic_load(p, __ATOMIC_RELAXED, __HIP_MEMORY_SCOPE_AGENT);
}

// ---------------------------------------------------------------------------
// Fused kernel. Producer roles (wbf/bias2/cast) are R4's prep bodies +
// release protocol {stores -> __syncthreads (per-wave vmcnt drain) ->
// thread0 __threadfence (L2 wb) -> atomicAdd flag}. Consumer role (gemm,
// R4's proven 2-barrier 128x128 BK=64 body) spin-waits on {wall==1344,
// vcnt[its b's]==784} then acquires via __threadfence. Overlaps the two
// memory-underutilized phases that previously ran back-to-back.
// Deadlock-free: <=588 spinners, >=768 resident blocks (33 KB LDS -> 4/CU).
// ---------------------------------------------------------------------------
__global__ __launch_bounds__(256) void fused_kernel(
    const float* __restrict__ x, const float* __restrict__ wred,
    const float* __restrict__ wconv, const float* __restrict__ gamma,
    const float* __restrict__ beta, unsigned short* __restrict__ xbf,
    unsigned short* __restrict__ wbf, float2* __restrict__ pst,
    float2* __restrict__ bias2, int* __restrict__ flags,
    float* __restrict__ out) {
  __shared__ union {
    struct {
      unsigned short As[128 * 64];   // 16 KB
      unsigned short Bs[128 * 64];   // 16 KB
      float2 st[128];                // per-row (rs, nmu)
    } g;
    float xs[DIMC];
  } sm;

  const int blk = blockIdx.x;
  const int t = threadIdx.x;
  const int wv = t >> 6;
  const int lane = t & 63;

  if (blk < RB_BIAS) {                     // ---- wbf = bf16(gamma*w_red) ----
    int idx4 = blk * 256 + t;              // < 294912
    int e0 = idx4 * 4;
    int f = e0 % FDIM;
    float4 w = *reinterpret_cast<const float4*>(wred + e0);
    float4 g = *reinterpret_cast<const float4*>(gamma + f);
    ushort4v u;
    u.x = f2bf(w.x * g.x); u.y = f2bf(w.y * g.y);
    u.z = f2bf(w.z * g.z); u.w = f2bf(w.w * g.w);
    *reinterpret_cast<ushort4v*>(wbf + e0) = u;
    __syncthreads();                       // all waves' stores drained
    if (t == 0) { __threadfence(); atomicAdd(&flags[0], 1); }
  } else if (blk < RB_CAST) {              // ---- bias2 = (gsum, bias) ----
    int o = (blk - RB_BIAS) * 4 + wv;      // < 768
    const float* wr = wred + (size_t)o * FDIM;
    float sb = 0.f, sg = 0.f;
#pragma unroll
    for (int c = 0; c < 6; ++c) {
      int f = lane * 4 + c * 256;
      float4 w = *reinterpret_cast<const float4*>(wr + f);
      float4 be = *reinterpret_cast<const float4*>(beta + f);
      float4 ga = *reinterpret_cast<const float4*>(gamma + f);
      sb += w.x * be.x + w.y * be.y + w.z * be.z + w.w * be.w;
      sg += w.x * ga.x + w.y * ga.y + w.z * ga.z + w.w * ga.w;
    }
#pragma unroll
    for (int o2 = 32; o2 > 0; o2 >>= 1) {
      sb += __shfl_down(sb, o2);
      sg += __shfl_down(sg, o2);
    }
    if (lane == 0) bias2[o] = make_float2(sg, sb);
    __syncthreads();
    if (t == 0) { __threadfence(); atomicAdd(&flags[0], 1); }
  } else if (blk < RB_CLS) {               // ---- cast + partial stats ----
    const int cblk = blk - RB_CAST;        // 0..1567
    const int w = cblk * 4 + wv;           // 0..6271
    const int vid0 = w * 8 + (lane >> 4) * 2;   // even; pair stays in one b
    const int sub = lane & 15;
    float4 v[2][6];
    float s[2], s2[2];
#pragma unroll
    for (int r = 0; r < 2; ++r) {          // batch ALL loads first
      int vid = vid0 + r;
      int b = vid / 784;
      int ll = vid - b * 784;
      const float* src = x + ((size_t)b * LL + 1 + ll) * DIMC;
      s[r] = 0.f; s2[r] = 0.f;
#pragma unroll
      for (int c = 0; c < 6; ++c) {
        float4 vv = *reinterpret_cast<const float4*>(src + sub * 4 + c * 64);
        v[r][c] = vv;
        s[r]  += vv.x + vv.y + vv.z + vv.w;
        s2[r] += vv.x * vv.x + vv.y * vv.y + vv.z * vv.z + vv.w * vv.w;
      }
    }
#pragma unroll
    for (int r = 0; r < 2; ++r) {          // then the store stream
      unsigned short* dst = xbf + (size_t)(vid0 + r) * DIMC;
#pragma unroll
      for (int c = 0; c < 6; ++c) {
        float4 vv = v[r][c];
        union { ushort4v u4; __hip_bfloat162 h[2]; } u;
        u.h[0] = __float22bfloat162_rn(make_float2(vv.x, vv.y));
        u.h[1] = __float22bfloat162_rn(make_float2(vv.z, vv.w));
        *reinterpret_cast<ushort4v*>(dst + sub * 4 + c * 64) = u.u4;
      }
    }
#pragma unroll
    for (int o = 1; o < 16; o <<= 1) {     // 16-lane group reduce, ILP-4
#pragma unroll
      for (int r = 0; r < 2; ++r) {
        s[r]  += __shfl_xor(s[r], o);
        s2[r] += __shfl_xor(s2[r], o);
      }
    }
    if (sub == 0) {
      float4 pp = make_float4(s[0], s2[0], s[1], s2[1]);
      *reinterpret_cast<float4*>(&pst[vid0]) = pp;   // vid0 even: 16B aligned
    }
    __syncthreads();                       // all waves' stores drained
    if (t == 0) {
      __threadfence();                     // L2 writeback: device-visible
      int v0 = cblk * 32;                  // block covers vids [v0, v0+32)
      int b0 = v0 / 784, b1 = (v0 + 31) / 784;
      if (b0 == b1) {
        atomicAdd(&flags[1 + b0], 32);
      } else {
        int c1 = b1 * 784 - v0;            // vids in b0
        atomicAdd(&flags[1 + b0], c1);
        atomicAdd(&flags[1 + b1], 32 - c1);
      }
    }
  } else if (blk < RB_GEMM) {              // ---- cls ----
    int idx = blk - RB_CLS;                // < 192
    int b = idx / 3;
    int ch = idx - b * 3;
    for (int c = t; c < DIMC; c += 256) sm.xs[c] = x[(size_t)b * LL * DIMC + c];
    __syncthreads();
    int o = ch * 256 + t;
    const float* wr = wconv + (size_t)o * DIMC;
    float a0 = 0.f, a1 = 0.f;
#pragma unroll 4
    for (int c = 0; c < DIMC; c += 8) {
      float4 w0 = *reinterpret_cast<const float4*>(wr + c);
      float4 w1 = *reinterpret_cast<const float4*>(wr + c + 4);
      float4 p0 = *reinterpret_cast<const float4*>(&sm.xs[c]);
      float4 p1 = *reinterpret_cast<const float4*>(&sm.xs[c + 4]);
      a0 += w0.x * p0.x + w0.y * p0.y + w0.z * p0.z + w0.w * p0.w;
      a1 += w1.x * p1.x + w1.y * p1.y + w1.z * p1.z + w1.w * p1.w;
    }
    out[(size_t)b * 197 * ODIM + o] = a0 + a1;
  } else {                                 // ---- gemm (R4 body + spin) ----
    // ---- chunked bijective XCD swizzle: NWG=588, q=73, r=4 ----
    const int NWG = (ODIM / 128) * (MROWS / 128);   // 588
    const int qq = NWG >> 3, rr = NWG & 7;
    int bid = blk - RB_GEMM;               // RB_GEMM%8==0: XCD map preserved
    int xcd = bid & 7, pos = bid >> 3;
    int wg = (xcd < rr) ? xcd * (qq + 1) + pos
                        : rr * (qq + 1) + (xcd - rr) * qq + pos;
    int my = wg / 6;                       // consecutive wg share my (A-panel)
    int nx = wg - my * 6;
    const int mBase = my * 128;
    const int nBase = nx * 128;

    // ---- spin until producers done (weights fully; casts of our b's) ----
    const int bf_ = mBase / NPATCH;
    const int bl_ = (mBase + 127) / NPATCH;
    if (t == 0) {
      while (flag_peek(&flags[0]) < WALL_TARGET) __builtin_amdgcn_s_sleep(2);
      while (flag_peek(&flags[1 + bf_]) < 784) __builtin_amdgcn_s_sleep(2);
      while (bl_ != bf_ && flag_peek(&flags[1 + bl_]) < 784)
        __builtin_amdgcn_s_sleep(2);
      __threadfence();                     // acquire: inv L1/L2
    }
    __syncthreads();

    // Prologue stats combine: thread r<128 -> row mBase+r's (rs, nmu).
    if (t < 128) {
      int m = mBase + t;
      int b = m / NPATCH;
      int n = m - b * NPATCH;
      int i = n / 14;
      int j = n - i * 14;
      int base = b * 784 + i * 56 + j * 2;
      float2 p0 = pst[base];
      float2 p1 = pst[base + 28];
      float2 p2 = pst[base + 1];
      float2 p3 = pst[base + 29];
      float s = p0.x + p1.x + p2.x + p3.x;
      float s2 = p0.y + p1.y + p2.y + p3.y;
      float mu = s * (1.f / FDIM);
      float var = s2 * (1.f / FDIM) - mu * mu;
      float rs = rsqrtf(var + 1e-5f);
      sm.g.st[t] = make_float2(rs, -mu * rs);
    }

    // Staging precompute: slot s = p*256+t -> row r=s>>3, chunk c0=s&7;
    // source chunk cs = c0 ^ (r&7); LDS dest = s*16 bytes.
    const unsigned short* agp[4];
    const unsigned short* bgp[4];
    unsigned int ldso[4];
#pragma unroll
    for (int p = 0; p < 4; ++p) {
      int s = p * 256 + t;
      int r = s >> 3;
      int cs = (s & 7) ^ (r & 7);
      int m = mBase + r;
      int b = m / NPATCH;
      int n = m - b * NPATCH;
      int i = n / 14;
      int j = n - i * 14;
      agp[p] = xbf + ((size_t)b * 784 + i * 56 + j * 2) * DIMC + cs * 8;
      bgp[p] = wbf + (size_t)(nBase + r) * FDIM + cs * 8;
      ldso[p] = (unsigned)s * 8;
    }

    const int ln15 = lane & 15;
    const int quad = lane >> 4;
    const int wm = wv >> 1;
    const int wn = wv & 1;

    unsigned int aoff[4][2], boff[4][2];
#pragma unroll
    for (int mt = 0; mt < 4; ++mt) {
#pragma unroll
      for (int h = 0; h < 2; ++h) {
        int rA = wm * 64 + mt * 16 + ln15;
        aoff[mt][h] = (unsigned)(rA * 64 + (((h * 4 + quad) ^ (rA & 7)) * 8));
        int rB = wn * 64 + mt * 16 + ln15;
        boff[mt][h] = (unsigned)(rB * 64 + (((h * 4 + quad) ^ (rB & 7)) * 8));
      }
    }

    floatx4 acc[4][4];
#pragma unroll
    for (int mt = 0; mt < 4; ++mt)
#pragma unroll
      for (int nt = 0; nt < 4; ++nt)
        acc[mt][nt] = floatx4{0.f, 0.f, 0.f, 0.f};

    for (int kt = 0; kt < FDIM / 64; ++kt) {
      // quadrant q = kt/6 (uniform), in-quadrant col kk*64
      int q = kt / 6;
      int kk = kt - q * 6;
      int ao = ((q & 1) * 28 + ((q >> 1) & 1)) * DIMC + kk * 64;
      if (kt) __syncthreads();             // all waves done reading prev tile
#pragma unroll
      for (int p = 0; p < 4; ++p) {
        gload_lds16(agp[p] + ao, &sm.g.As[ldso[p]]);
        gload_lds16(bgp[p], &sm.g.Bs[ldso[p]]);
        bgp[p] += 64;
      }
      __syncthreads();                     // compiler adds vmcnt(0) drain

#pragma unroll
      for (int h = 0; h < 2; ++h) {
        bf16x8 af[4], bfr[4];
#pragma unroll
        for (int mt = 0; mt < 4; ++mt)
          af[mt] = *reinterpret_cast<const bf16x8*>(&sm.g.As[aoff[mt][h]]);
#pragma unroll
        for (int nt = 0; nt < 4; ++nt)
          bfr[nt] = *reinterpret_cast<const bf16x8*>(&sm.g.Bs[boff[nt][h]]);
#pragma unroll
        for (int mt = 0; mt < 4; ++mt)
#pragma unroll
          for (int nt = 0; nt < 4; ++nt)
            acc[mt][nt] = __builtin_amdgcn_mfma_f32_16x16x32_bf16(
                af[mt], bfr[nt], acc[mt][nt], 0, 0, 0);
      }
    }

    // Epilogue. C/D: col = ln15, row = quad*4 + reg  [m89/m91].
    // C = rs*acc + nmu*gsum + bias.
    float2 gb[4];
#pragma unroll
    for (int nt = 0; nt < 4; ++nt)
      gb[nt] = bias2[nBase + wn * 64 + nt * 16 + ln15];
#pragma unroll
    for (int mt = 0; mt < 4; ++mt) {
#pragma unroll
      for (int r = 0; r < 4; ++r) {
        int rloc = wm * 64 + mt * 16 + quad * 4 + r;
        float2 sn = sm.g.st[rloc];         // (rs, nmu)
        int m = mBase + rloc;
        int b = m / NPATCH;
        int n = m - b * NPATCH;
        float* orow = out + ((size_t)b * 197 + 1 + n) * ODIM + nBase + wn * 64;
#pragma unroll
        for (int nt = 0; nt < 4; ++nt) {
          float val = fmaf(acc[mt][nt][r], sn.x,
                           fmaf(sn.y, gb[nt].x, gb[nt].y));
          __builtin_nontemporal_store(val, &orow[nt * 16 + ln15]);
        }
      }
    }
  }
}

extern "C" void kernel_launch(void* const* d_in, const int* in_sizes, int n_in,
                              void* d_out, int out_size, void* d_ws, size_t ws_size,
                              hipStream_t stream) {
  const float* x     = (const float*)d_in[0];   // (64, 785, 384)
  const float* wred  = (const float*)d_in[1];   // (768, 1536)
  const float* wconv = (const float*)d_in[2];   // (768, 384)
  const float* gamma = (const float*)d_in[3];   // (1536,)
  const float* beta  = (const float*)d_in[4];   // (1536,)
  float* out = (float*)d_out;                   // (64, 197, 768)

  unsigned short* xbf = (unsigned short*)d_ws;
  unsigned short* wbf = (unsigned short*)((char*)d_ws + WS_WBF_OFF);
  float2* pst         = (float2*)((char*)d_ws + WS_PST_OFF);
  float2* bias2       = (float2*)((char*)d_ws + WS_B2_OFF);
  int* flags          = (int*)((char*)d_ws + WS_FLAG_OFF);

  hipMemsetAsync(flags, 0, 65 * sizeof(int), stream);   // zero handoff flags
  fused_kernel<<<dim3(TOTAL_BLOCKS), 256, 0, stream>>>(
      x, wred, wconv, gamma, beta, xbf, wbf, pst, bias2, flags, out);
}

// Round 10
// 176.699 us; speedup vs baseline: 1.9631x; 1.9631x over previous
//
#include <hip/hip_runtime.h>
#include <hip/hip_bf16.h>

#define DIMC 384          // C
#define LL 785            // 1 + 28*28
#define FDIM 1536         // 4*C  (GEMM K)
#define ODIM 768          // 2*C  (GEMM N)
#define NPATCH 196        // 14*14
#define MROWS 12544       // B*196 (GEMM M)
#define BATCH 64

typedef __attribute__((ext_vector_type(8))) short bf16x8;
typedef __attribute__((ext_vector_type(4))) float floatx4;
typedef __attribute__((ext_vector_type(4))) unsigned short ushort4v;

// ws layout (bytes):
//   xbf   u16[50176*384]  @ 0           (38,535,168 B)  bf16(raw x feature rows)
//   wbf   u16[768*1536]   @ 38535168    ( 2,359,296 B)  bf16(gamma * w_red)
//   pst   f32x2[50176]    @ 40894464    (   401,408 B)  per-(b,l) partial (s,s2)
//   bias2 f32x2[768]      @ 41295872    (     6,144 B)  (gsum, bias) per o
#define WS_WBF_OFF  38535168
#define WS_PST_OFF  40894464
#define WS_B2_OFF   41295872

// prep role bases (cls first: latency-bound blocks hide under cast stream)
#define PB_CLS   0
#define PB_CAST  192     // 784 cast blocks (64 vectors each)
#define PB_BIAS  976     // 192 bias blocks
#define PB_WBF   1168    // 1152 wbf blocks
#define PREP_BLOCKS 2320

__device__ __forceinline__ unsigned short f2bf(float f) {
  union { float f; unsigned int u; } v; v.f = f;
  unsigned int u = v.u + 0x7fffu + ((v.u >> 16) & 1u);   // RNE
  return (unsigned short)(u >> 16);
}

__device__ __forceinline__ void gload_lds16(const void* g, void* l) {
  __builtin_amdgcn_global_load_lds(
      (const __attribute__((address_space(1))) unsigned int*)g,
      (__attribute__((address_space(3))) unsigned int*)l, 16, 0, 0);
}

// ---------------------------------------------------------------------------
// Prep kernel (R4 structure; cast widened to 4 vectors / quarter-wave).
//  cast+pstat: FOUR consecutive (b,l) vectors per quarter-wave; all 24
//    float4 loads batched before any store (24 outstanding VMEM/thread;
//    values park in the unified VGPR/AGPR file). Stores depend only on
//    loads -- stats (s,s2) accumulate off the store path, 4-level 16-lane
//    shfl at the end. LayerNorm is applied in the GEMM epilogue (affine).
//  bias2: (gsum[o], bias[o]);  wbf: bf16(gamma*w_red);  cls: wconv @ x[b,0].
// ---------------------------------------------------------------------------
__global__ __launch_bounds__(256) void prep_kernel(
    const float* __restrict__ x, const float* __restrict__ wred,
    const float* __restrict__ wconv, const float* __restrict__ gamma,
    const float* __restrict__ beta, unsigned short* __restrict__ xbf,
    unsigned short* __restrict__ wbf, float2* __restrict__ pst,
    float2* __restrict__ bias2, float* __restrict__ out) {
  const int blk = blockIdx.x;
  const int t = threadIdx.x;
  const int wv = t >> 6;
  const int lane = t & 63;

  if (blk >= PB_CAST && blk < PB_BIAS) {  // ---- cast + partial stats ----
    const int qw = ((blk - PB_CAST) * 4 + wv) * 4 + (lane >> 4);
    const int vid0 = qw * 4;              // 4 consecutive vids; 784%4==0 ->
    const int sub = lane & 15;            // group never crosses a batch b
    const int b = vid0 / 784;
    const int ll0 = vid0 - b * 784;
    const float* src = x + ((size_t)b * LL + 1 + ll0) * DIMC;
    float4 v[4][6];
    float s[4], s2[4];
#pragma unroll
    for (int r = 0; r < 4; ++r) {          // batch ALL 24 loads first
      s[r] = 0.f; s2[r] = 0.f;
#pragma unroll
      for (int c = 0; c < 6; ++c) {
        float4 vv = *reinterpret_cast<const float4*>(
            src + r * DIMC + sub * 4 + c * 64);
        v[r][c] = vv;
        s[r]  += vv.x + vv.y + vv.z + vv.w;
        s2[r] += vv.x * vv.x + vv.y * vv.y + vv.z * vv.z + vv.w * vv.w;
      }
    }
#pragma unroll
    for (int r = 0; r < 4; ++r) {          // then the store stream
      unsigned short* dst = xbf + (size_t)(vid0 + r) * DIMC;
#pragma unroll
      for (int c = 0; c < 6; ++c) {
        float4 vv = v[r][c];
        union { ushort4v u4; __hip_bfloat162 h[2]; } u;
        u.h[0] = __float22bfloat162_rn(make_float2(vv.x, vv.y));
        u.h[1] = __float22bfloat162_rn(make_float2(vv.z, vv.w));
        *reinterpret_cast<ushort4v*>(dst + sub * 4 + c * 64) = u.u4;
      }
    }
#pragma unroll
    for (int o = 1; o < 16; o <<= 1) {     // 16-lane group reduce, ILP-8
#pragma unroll
      for (int r = 0; r < 4; ++r) {
        s[r]  += __shfl_xor(s[r], o);
        s2[r] += __shfl_xor(s2[r], o);
      }
    }
    if (sub == 0) {                        // vid0%4==0: 16B-aligned stores
      *reinterpret_cast<float4*>(&pst[vid0]) =
          make_float4(s[0], s2[0], s[1], s2[1]);
      *reinterpret_cast<float4*>(&pst[vid0 + 2]) =
          make_float4(s[2], s2[2], s[3], s2[3]);
    }
  } else if (blk < PB_CAST) {              // ---- cls ----
    __shared__ float xs[DIMC];
    int idx = blk;                         // < 192
    int b = idx / 3;
    int ch = idx - b * 3;
    for (int c = t; c < DIMC; c += 256) xs[c] = x[(size_t)b * LL * DIMC + c];
    __syncthreads();
    int o = ch * 256 + t;
    const float* wr = wconv + (size_t)o * DIMC;
    float a0 = 0.f, a1 = 0.f;
#pragma unroll 4
    for (int c = 0; c < DIMC; c += 8) {
      float4 w0 = *reinterpret_cast<const float4*>(wr + c);
      float4 w1 = *reinterpret_cast<const float4*>(wr + c + 4);
      float4 p0 = *reinterpret_cast<const float4*>(&xs[c]);
      float4 p1 = *reinterpret_cast<const float4*>(&xs[c + 4]);
      a0 += w0.x * p0.x + w0.y * p0.y + w0.z * p0.z + w0.w * p0.w;
      a1 += w1.x * p1.x + w1.y * p1.y + w1.z * p1.z + w1.w * p1.w;
    }
    out[(size_t)b * 197 * ODIM + o] = a0 + a1;
  } else if (blk < PB_WBF) {               // ---- bias2 = (gsum, bias) ----
    int o = (blk - PB_BIAS) * 4 + wv;      // < 768
    const float* wr = wred + (size_t)o * FDIM;
    float sb = 0.f, sg = 0.f;
#pragma unroll
    for (int c = 0; c < 6; ++c) {
      int f = lane * 4 + c * 256;
      float4 w = *reinterpret_cast<const float4*>(wr + f);
      float4 be = *reinterpret_cast<const float4*>(beta + f);
      float4 ga = *reinterpret_cast<const float4*>(gamma + f);
      sb += w.x * be.x + w.y * be.y + w.z * be.z + w.w * be.w;
      sg += w.x * ga.x + w.y * ga.y + w.z * ga.z + w.w * ga.w;
    }
#pragma unroll
    for (int o2 = 32; o2 > 0; o2 >>= 1) {
      sb += __shfl_down(sb, o2);
      sg += __shfl_down(sg, o2);
    }
    if (lane == 0) bias2[o] = make_float2(sg, sb);
  } else {                                 // ---- wbf = bf16(gamma*w_red) ----
    int idx4 = (blk - PB_WBF) * 256 + t;   // < 294912
    int e0 = idx4 * 4;
    int f = e0 % FDIM;
    float4 w = *reinterpret_cast<const float4*>(wred + e0);
    float4 g = *reinterpret_cast<const float4*>(gamma + f);
    ushort4v u;
    u.x = f2bf(w.x * g.x); u.y = f2bf(w.y * g.y);
    u.z = f2bf(w.z * g.z); u.w = f2bf(w.w * g.w);
    *reinterpret_cast<ushort4v*>(wbf + e0) = u;
  }
}

// ---------------------------------------------------------------------------
// GEMM (R4 verbatim — measured 46.1 us, MfmaUtil 24.4, BANK_CONFLICT 0).
// Tile 128x128, BK=64, 256 thr, proven 2-barrier schedule, 33 KB LDS.
// A k-slice (BK=64) lies in ONE quadrant (384 = 6*64): per-row source =
// fixed xbf row base + per-kt scalar offset. Epilogue applies LayerNorm
// affinely: C = rs[m]*acc + nmu[m]*gsum[o] + bias[o]; per-row (rs,nmu)
// combined from 4 quadrant partials in the prologue (hides under K loop).
// ---------------------------------------------------------------------------
__global__ __launch_bounds__(256) void gemm_kernel(
    const unsigned short* __restrict__ xbf,
    const unsigned short* __restrict__ wbf,
    const float2* __restrict__ pst, const float2* __restrict__ bias2,
    float* __restrict__ out) {
  __shared__ unsigned short As[128 * 64];   // 16 KB
  __shared__ unsigned short Bs[128 * 64];   // 16 KB
  __shared__ float2 st[128];                // per-row (rs, nmu)

  const int t = threadIdx.x;

  // ---- chunked bijective XCD swizzle: NWG=588, q=73, r=4 ----
  const int NWG = (ODIM / 128) * (MROWS / 128);   // 588
  const int qq = NWG >> 3, rr = NWG & 7;
  int bid = blockIdx.x;
  int xcd = bid & 7, pos = bid >> 3;
  int wg = (xcd < rr) ? xcd * (qq + 1) + pos
                      : rr * (qq + 1) + (xcd - rr) * qq + pos;
  int my = wg / 6;                        // consecutive wg share my (A-panel)
  int nx = wg - my * 6;
  const int mBase = my * 128;
  const int nBase = nx * 128;

  // Prologue stats combine: thread r<128 -> row mBase+r's (rs, nmu).
  if (t < 128) {
    int m = mBase + t;
    int b = m / NPATCH;
    int n = m - b * NPATCH;
    int i = n / 14;
    int j = n - i * 14;
    int base = b * 784 + i * 56 + j * 2;
    float2 p0 = pst[base];
    float2 p1 = pst[base + 28];
    float2 p2 = pst[base + 1];
    float2 p3 = pst[base + 29];
    float s = p0.x + p1.x + p2.x + p3.x;
    float s2 = p0.y + p1.y + p2.y + p3.y;
    float mu = s * (1.f / FDIM);
    float var = s2 * (1.f / FDIM) - mu * mu;
    float rs = rsqrtf(var + 1e-5f);
    st[t] = make_float2(rs, -mu * rs);
  }

  // Staging precompute: slot s = p*256+t -> row r=s>>3, chunk c0=s&7;
  // source chunk cs = c0 ^ (r&7) (XOR swizzle); LDS dest = s*16 bytes.
  const unsigned short* agp[4];
  const unsigned short* bgp[4];
  unsigned int ldso[4];
#pragma unroll
  for (int p = 0; p < 4; ++p) {
    int s = p * 256 + t;
    int r = s >> 3;
    int cs = (s & 7) ^ (r & 7);
    int m = mBase + r;
    int b = m / NPATCH;
    int n = m - b * NPATCH;
    int i = n / 14;
    int j = n - i * 14;
    agp[p] = xbf + ((size_t)b * 784 + i * 56 + j * 2) * DIMC + cs * 8;
    bgp[p] = wbf + (size_t)(nBase + r) * FDIM + cs * 8;
    ldso[p] = (unsigned)s * 8;
  }

  const int wv = t >> 6;
  const int lane = t & 63;
  const int ln15 = lane & 15;
  const int quad = lane >> 4;
  const int wm = wv >> 1;
  const int wn = wv & 1;

  unsigned int aoff[4][2], boff[4][2];
#pragma unroll
  for (int mt = 0; mt < 4; ++mt) {
#pragma unroll
    for (int h = 0; h < 2; ++h) {
      int rA = wm * 64 + mt * 16 + ln15;
      aoff[mt][h] = (unsigned)(rA * 64 + (((h * 4 + quad) ^ (rA & 7)) * 8));
      int rB = wn * 64 + mt * 16 + ln15;
      boff[mt][h] = (unsigned)(rB * 64 + (((h * 4 + quad) ^ (rB & 7)) * 8));
    }
  }

  floatx4 acc[4][4];
#pragma unroll
  for (int mt = 0; mt < 4; ++mt)
#pragma unroll
    for (int nt = 0; nt < 4; ++nt)
      acc[mt][nt] = floatx4{0.f, 0.f, 0.f, 0.f};

  for (int kt = 0; kt < FDIM / 64; ++kt) {
    // quadrant q = kt/6 (uniform SALU), in-quadrant col kk*64
    int q = kt / 6;
    int kk = kt - q * 6;
    int ao = ((q & 1) * 28 + ((q >> 1) & 1)) * DIMC + kk * 64;
    if (kt) __syncthreads();             // all waves done reading prev tile
#pragma unroll
    for (int p = 0; p < 4; ++p) {
      gload_lds16(agp[p] + ao, &As[ldso[p]]);
      gload_lds16(bgp[p], &Bs[ldso[p]]);
      bgp[p] += 64;
    }
    __syncthreads();                     // compiler adds vmcnt(0) drain

#pragma unroll
    for (int h = 0; h < 2; ++h) {
      bf16x8 af[4], bfr[4];
#pragma unroll
      for (int mt = 0; mt < 4; ++mt)
        af[mt] = *reinterpret_cast<const bf16x8*>(&As[aoff[mt][h]]);
#pragma unroll
      for (int nt = 0; nt < 4; ++nt)
        bfr[nt] = *reinterpret_cast<const bf16x8*>(&Bs[boff[nt][h]]);
#pragma unroll
      for (int mt = 0; mt < 4; ++mt)
#pragma unroll
        for (int nt = 0; nt < 4; ++nt)
          acc[mt][nt] = __builtin_amdgcn_mfma_f32_16x16x32_bf16(
              af[mt], bfr[nt], acc[mt][nt], 0, 0, 0);
    }
  }

  // Epilogue. C/D: col = ln15, row = quad*4 + reg  [m89/m91].
  // C = rs*acc + nmu*gsum + bias.
  float2 gb[4];
#pragma unroll
  for (int nt = 0; nt < 4; ++nt)
    gb[nt] = bias2[nBase + wn * 64 + nt * 16 + ln15];
#pragma unroll
  for (int mt = 0; mt < 4; ++mt) {
#pragma unroll
    for (int r = 0; r < 4; ++r) {
      int rloc = wm * 64 + mt * 16 + quad * 4 + r;
      float2 sn = st[rloc];              // (rs, nmu)
      int m = mBase + rloc;
      int b = m / NPATCH;
      int n = m - b * NPATCH;
      float* orow = out + ((size_t)b * 197 + 1 + n) * ODIM + nBase + wn * 64;
#pragma unroll
      for (int nt = 0; nt < 4; ++nt) {
        float val = fmaf(acc[mt][nt][r], sn.x,
                         fmaf(sn.y, gb[nt].x, gb[nt].y));
        __builtin_nontemporal_store(val, &orow[nt * 16 + ln15]);
      }
    }
  }
}

extern "C" void kernel_launch(void* const* d_in, const int* in_sizes, int n_in,
                              void* d_out, int out_size, void* d_ws, size_t ws_size,
                              hipStream_t stream) {
  const float* x     = (const float*)d_in[0];   // (64, 785, 384)
  const float* wred  = (const float*)d_in[1];   // (768, 1536)
  const float* wconv = (const float*)d_in[2];   // (768, 384)
  const float* gamma = (const float*)d_in[3];   // (1536,)
  const float* beta  = (const float*)d_in[4];   // (1536,)
  float* out = (float*)d_out;                   // (64, 197, 768)

  unsigned short* xbf = (unsigned short*)d_ws;
  unsigned short* wbf = (unsigned short*)((char*)d_ws + WS_WBF_OFF);
  float2* pst         = (float2*)((char*)d_ws + WS_PST_OFF);
  float2* bias2       = (float2*)((char*)d_ws + WS_B2_OFF);

  prep_kernel<<<dim3(PREP_BLOCKS), 256, 0, stream>>>(x, wred, wconv, gamma,
                                                     beta, xbf, wbf, pst,
                                                     bias2, out);
  gemm_kernel<<<dim3((ODIM / 128) * (MROWS / 128)), 256, 0, stream>>>(
      xbf, wbf, pst, bias2, out);
}

// Round 11
// 172.825 us; speedup vs baseline: 2.0071x; 1.0224x over previous
//
#include <hip/hip_runtime.h>
#include <hip/hip_bf16.h>

#define DIMC 384          // C
#define LL 785            // 1 + 28*28
#define FDIM 1536         // 4*C  (GEMM K)
#define ODIM 768          // 2*C  (GEMM N)
#define NPATCH 196        // 14*14
#define MROWS 12544       // B*196 (GEMM M)
#define BATCH 64

typedef __attribute__((ext_vector_type(8))) short bf16x8;
typedef __attribute__((ext_vector_type(4))) float floatx4;
typedef __attribute__((ext_vector_type(4))) unsigned short ushort4v;
typedef __attribute__((ext_vector_type(8))) unsigned short ushort8v;

// ws layout (bytes):
//   xbf   u16[50176*384]  @ 0           (38,535,168 B)  bf16(raw x feature rows)
//   wbf   u16[768*1536]   @ 38535168    ( 2,359,296 B)  bf16(gamma * w_red)
//   pst   f32x2[50176]    @ 40894464    (   401,408 B)  per-(b,l) partial (s,s2)
//   bias2 f32x2[768]      @ 41295872    (     6,144 B)  (gsum, bias) per o
#define WS_WBF_OFF  38535168
#define WS_PST_OFF  40894464
#define WS_B2_OFF   41295872

// prep roles, 192-thread blocks (cls first: latency blocks hide under cast)
#define PB_CLS   0       // 256 blocks  (64 b x 4 chunks of 192)
#define PB_CAST  256     // 12544 blocks (4 vectors each)
#define PB_BIAS  12800   // 256 blocks  (3 o each)
#define PB_WBF   13056   // 1536 blocks
#define PREP_BLOCKS 14592

__device__ __forceinline__ unsigned short f2bf(float f) {
  union { float f; unsigned int u; } v; v.f = f;
  unsigned int u = v.u + 0x7fffu + ((v.u >> 16) & 1u);   // RNE
  return (unsigned short)(u >> 16);
}

__device__ __forceinline__ void gload_lds16(const void* g, void* l) {
  __builtin_amdgcn_global_load_lds(
      (const __attribute__((address_space(1))) unsigned int*)g,
      (__attribute__((address_space(3))) unsigned int*)l, 16, 0, 0);
}

// ---------------------------------------------------------------------------
// Prep kernel, 192-thread blocks.
//  cast+pstat (the 77+38 MB bulk): block handles 4 consecutive (b,l)
//    vectors; thread t owns 8 CONSECUTIVE floats (vid=t/48, pos=(t%48)*8).
//    Loads: 2xfloat4/lane, 48 lanes cover 1536 B contiguously. Stores: ONE
//    16-B ushort8/lane, consecutive lanes -> consecutive addresses (full
//    1 KB/wave store instructions -- the fill-kernel pattern that hits
//    6.6 TB/s, vs the old 8-B ushort4 at half width). Stats fully off the
//    hot path: per-lane partials -> LDS -> 4 leader threads combine 48.
//  bias2/wbf/cls: as before, re-dimensioned to 192 threads.
// ---------------------------------------------------------------------------
__global__ __launch_bounds__(192) void prep_kernel(
    const float* __restrict__ x, const float* __restrict__ wred,
    const float* __restrict__ wconv, const float* __restrict__ gamma,
    const float* __restrict__ beta, unsigned short* __restrict__ xbf,
    unsigned short* __restrict__ wbf, float2* __restrict__ pst,
    float2* __restrict__ bias2, float* __restrict__ out) {
  const int blk = blockIdx.x;
  const int t = threadIdx.x;

  if (blk >= PB_CAST && blk < PB_BIAS) {  // ---- cast + partial stats ----
    __shared__ float2 sp[192];
    const int vid0 = (blk - PB_CAST) * 4;  // 4|784: block stays in one b
    const int vv = t / 48;
    const int pos = (t - vv * 48) * 8;
    const int vid = vid0 + vv;
    const int b = vid / 784;
    const int ll = vid - b * 784;
    const float* src = x + ((size_t)b * LL + 1 + ll) * DIMC + pos;
    float4 a0 = *reinterpret_cast<const float4*>(src);
    float4 a1 = *reinterpret_cast<const float4*>(src + 4);
    float s  = a0.x + a0.y + a0.z + a0.w + a1.x + a1.y + a1.z + a1.w;
    float s2 = a0.x * a0.x + a0.y * a0.y + a0.z * a0.z + a0.w * a0.w
             + a1.x * a1.x + a1.y * a1.y + a1.z * a1.z + a1.w * a1.w;
    union { ushort8v u8; __hip_bfloat162 h[4]; } u;
    u.h[0] = __float22bfloat162_rn(make_float2(a0.x, a0.y));
    u.h[1] = __float22bfloat162_rn(make_float2(a0.z, a0.w));
    u.h[2] = __float22bfloat162_rn(make_float2(a1.x, a1.y));
    u.h[3] = __float22bfloat162_rn(make_float2(a1.z, a1.w));
    *reinterpret_cast<ushort8v*>(xbf + (size_t)vid * DIMC + pos) = u.u8;
    sp[t] = make_float2(s, s2);
    __syncthreads();
    if (t < 4) {                           // combine 48 partials per vector
      float cs = 0.f, cs2 = 0.f;
#pragma unroll
      for (int k = 0; k < 48; ++k) {
        float2 p = sp[t * 48 + k];
        cs += p.x; cs2 += p.y;
      }
      pst[vid0 + t] = make_float2(cs, cs2);
    }
  } else if (blk < PB_CAST) {              // ---- cls ----
    __shared__ float xs[DIMC];
    int idx = blk;                         // < 256
    int b = idx >> 2;
    int ch = idx & 3;
    for (int c = t; c < DIMC; c += 192) xs[c] = x[(size_t)b * LL * DIMC + c];
    __syncthreads();
    int o = ch * 192 + t;
    const float* wr = wconv + (size_t)o * DIMC;
    float a0 = 0.f, a1 = 0.f;
#pragma unroll 4
    for (int c = 0; c < DIMC; c += 8) {
      float4 w0 = *reinterpret_cast<const float4*>(wr + c);
      float4 w1 = *reinterpret_cast<const float4*>(wr + c + 4);
      float4 p0 = *reinterpret_cast<const float4*>(&xs[c]);
      float4 p1 = *reinterpret_cast<const float4*>(&xs[c + 4]);
      a0 += w0.x * p0.x + w0.y * p0.y + w0.z * p0.z + w0.w * p0.w;
      a1 += w1.x * p1.x + w1.y * p1.y + w1.z * p1.z + w1.w * p1.w;
    }
    out[(size_t)b * 197 * ODIM + o] = a0 + a1;
  } else if (blk < PB_WBF) {               // ---- bias2 = (gsum, bias) ----
    const int wv = t >> 6;
    const int lane = t & 63;
    int o = (blk - PB_BIAS) * 3 + wv;      // < 768
    const float* wr = wred + (size_t)o * FDIM;
    float sb = 0.f, sg = 0.f;
#pragma unroll
    for (int c = 0; c < 6; ++c) {
      int f = lane * 4 + c * 256;
      float4 w = *reinterpret_cast<const float4*>(wr + f);
      float4 be = *reinterpret_cast<const float4*>(beta + f);
      float4 ga = *reinterpret_cast<const float4*>(gamma + f);
      sb += w.x * be.x + w.y * be.y + w.z * be.z + w.w * be.w;
      sg += w.x * ga.x + w.y * ga.y + w.z * ga.z + w.w * ga.w;
    }
#pragma unroll
    for (int o2 = 32; o2 > 0; o2 >>= 1) {
      sb += __shfl_down(sb, o2);
      sg += __shfl_down(sg, o2);
    }
    if (lane == 0) bias2[o] = make_float2(sg, sb);
  } else {                                 // ---- wbf = bf16(gamma*w_red) ----
    int idx4 = (blk - PB_WBF) * 192 + t;   // < 294912
    int e0 = idx4 * 4;
    int f = e0 % FDIM;
    float4 w = *reinterpret_cast<const float4*>(wred + e0);
    float4 g = *reinterpret_cast<const float4*>(gamma + f);
    ushort4v u;
    u.x = f2bf(w.x * g.x); u.y = f2bf(w.y * g.y);
    u.z = f2bf(w.z * g.z); u.w = f2bf(w.w * g.w);
    *reinterpret_cast<ushort4v*>(wbf + e0) = u;
  }
}

// ---------------------------------------------------------------------------
// GEMM (R4 verbatim — measured 46.1 us, MfmaUtil 24.4, BANK_CONFLICT 0).
// Tile 128x128, BK=64, 256 thr, proven 2-barrier schedule, 33 KB LDS.
// Affine-LN epilogue: C = rs[m]*acc + nmu[m]*gsum[o] + bias[o].
// ---------------------------------------------------------------------------
__global__ __launch_bounds__(256) void gemm_kernel(
    const unsigned short* __restrict__ xbf,
    const unsigned short* __restrict__ wbf,
    const float2* __restrict__ pst, const float2* __restrict__ bias2,
    float* __restrict__ out) {
  __shared__ unsigned short As[128 * 64];   // 16 KB
  __shared__ unsigned short Bs[128 * 64];   // 16 KB
  __shared__ float2 st[128];                // per-row (rs, nmu)

  const int t = threadIdx.x;

  // ---- chunked bijective XCD swizzle: NWG=588, q=73, r=4 ----
  const int NWG = (ODIM / 128) * (MROWS / 128);   // 588
  const int qq = NWG >> 3, rr = NWG & 7;
  int bid = blockIdx.x;
  int xcd = bid & 7, pos = bid >> 3;
  int wg = (xcd < rr) ? xcd * (qq + 1) + pos
                      : rr * (qq + 1) + (xcd - rr) * qq + pos;
  int my = wg / 6;                        // consecutive wg share my (A-panel)
  int nx = wg - my * 6;
  const int mBase = my * 128;
  const int nBase = nx * 128;

  // Prologue stats combine: thread r<128 -> row mBase+r's (rs, nmu).
  if (t < 128) {
    int m = mBase + t;
    int b = m / NPATCH;
    int n = m - b * NPATCH;
    int i = n / 14;
    int j = n - i * 14;
    int base = b * 784 + i * 56 + j * 2;
    float2 p0 = pst[base];
    float2 p1 = pst[base + 28];
    float2 p2 = pst[base + 1];
    float2 p3 = pst[base + 29];
    float s = p0.x + p1.x + p2.x + p3.x;
    float s2 = p0.y + p1.y + p2.y + p3.y;
    float mu = s * (1.f / FDIM);
    float var = s2 * (1.f / FDIM) - mu * mu;
    float rs = rsqrtf(var + 1e-5f);
    st[t] = make_float2(rs, -mu * rs);
  }

  // Staging precompute: slot s = p*256+t -> row r=s>>3, chunk c0=s&7;
  // source chunk cs = c0 ^ (r&7) (XOR swizzle); LDS dest = s*16 bytes.
  const unsigned short* agp[4];
  const unsigned short* bgp[4];
  unsigned int ldso[4];
#pragma unroll
  for (int p = 0; p < 4; ++p) {
    int s = p * 256 + t;
    int r = s >> 3;
    int cs = (s & 7) ^ (r & 7);
    int m = mBase + r;
    int b = m / NPATCH;
    int n = m - b * NPATCH;
    int i = n / 14;
    int j = n - i * 14;
    agp[p] = xbf + ((size_t)b * 784 + i * 56 + j * 2) * DIMC + cs * 8;
    bgp[p] = wbf + (size_t)(nBase + r) * FDIM + cs * 8;
    ldso[p] = (unsigned)s * 8;
  }

  const int wv = t >> 6;
  const int lane = t & 63;
  const int ln15 = lane & 15;
  const int quad = lane >> 4;
  const int wm = wv >> 1;
  const int wn = wv & 1;

  unsigned int aoff[4][2], boff[4][2];
#pragma unroll
  for (int mt = 0; mt < 4; ++mt) {
#pragma unroll
    for (int h = 0; h < 2; ++h) {
      int rA = wm * 64 + mt * 16 + ln15;
      aoff[mt][h] = (unsigned)(rA * 64 + (((h * 4 + quad) ^ (rA & 7)) * 8));
      int rB = wn * 64 + mt * 16 + ln15;
      boff[mt][h] = (unsigned)(rB * 64 + (((h * 4 + quad) ^ (rB & 7)) * 8));
    }
  }

  floatx4 acc[4][4];
#pragma unroll
  for (int mt = 0; mt < 4; ++mt)
#pragma unroll
    for (int nt = 0; nt < 4; ++nt)
      acc[mt][nt] = floatx4{0.f, 0.f, 0.f, 0.f};

  for (int kt = 0; kt < FDIM / 64; ++kt) {
    // quadrant q = kt/6 (uniform SALU), in-quadrant col kk*64
    int q = kt / 6;
    int kk = kt - q * 6;
    int ao = ((q & 1) * 28 + ((q >> 1) & 1)) * DIMC + kk * 64;
    if (kt) __syncthreads();             // all waves done reading prev tile
#pragma unroll
    for (int p = 0; p < 4; ++p) {
      gload_lds16(agp[p] + ao, &As[ldso[p]]);
      gload_lds16(bgp[p], &Bs[ldso[p]]);
      bgp[p] += 64;
    }
    __syncthreads();                     // compiler adds vmcnt(0) drain

#pragma unroll
    for (int h = 0; h < 2; ++h) {
      bf16x8 af[4], bfr[4];
#pragma unroll
      for (int mt = 0; mt < 4; ++mt)
        af[mt] = *reinterpret_cast<const bf16x8*>(&As[aoff[mt][h]]);
#pragma unroll
      for (int nt = 0; nt < 4; ++nt)
        bfr[nt] = *reinterpret_cast<const bf16x8*>(&Bs[boff[nt][h]]);
#pragma unroll
      for (int mt = 0; mt < 4; ++mt)
#pragma unroll
        for (int nt = 0; nt < 4; ++nt)
          acc[mt][nt] = __builtin_amdgcn_mfma_f32_16x16x32_bf16(
              af[mt], bfr[nt], acc[mt][nt], 0, 0, 0);
    }
  }

  // Epilogue. C/D: col = ln15, row = quad*4 + reg  [m89/m91].
  // C = rs*acc + nmu*gsum + bias.
  float2 gb[4];
#pragma unroll
  for (int nt = 0; nt < 4; ++nt)
    gb[nt] = bias2[nBase + wn * 64 + nt * 16 + ln15];
#pragma unroll
  for (int mt = 0; mt < 4; ++mt) {
#pragma unroll
    for (int r = 0; r < 4; ++r) {
      int rloc = wm * 64 + mt * 16 + quad * 4 + r;
      float2 sn = st[rloc];              // (rs, nmu)
      int m = mBase + rloc;
      int b = m / NPATCH;
      int n = m - b * NPATCH;
      float* orow = out + ((size_t)b * 197 + 1 + n) * ODIM + nBase + wn * 64;
#pragma unroll
      for (int nt = 0; nt < 4; ++nt) {
        float val = fmaf(acc[mt][nt][r], sn.x,
                         fmaf(sn.y, gb[nt].x, gb[nt].y));
        __builtin_nontemporal_store(val, &orow[nt * 16 + ln15]);
      }
    }
  }
}

extern "C" void kernel_launch(void* const* d_in, const int* in_sizes, int n_in,
                              void* d_out, int out_size, void* d_ws, size_t ws_size,
                              hipStream_t stream) {
  const float* x     = (const float*)d_in[0];   // (64, 785, 384)
  const float* wred  = (const float*)d_in[1];   // (768, 1536)
  const float* wconv = (const float*)d_in[2];   // (768, 384)
  const float* gamma = (const float*)d_in[3];   // (1536,)
  const float* beta  = (const float*)d_in[4];   // (1536,)
  float* out = (float*)d_out;                   // (64, 197, 768)

  unsigned short* xbf = (unsigned short*)d_ws;
  unsigned short* wbf = (unsigned short*)((char*)d_ws + WS_WBF_OFF);
  float2* pst         = (float2*)((char*)d_ws + WS_PST_OFF);
  float2* bias2       = (float2*)((char*)d_ws + WS_B2_OFF);

  prep_kernel<<<dim3(PREP_BLOCKS), 192, 0, stream>>>(x, wred, wconv, gamma,
                                                     beta, xbf, wbf, pst,
                                                     bias2, out);
  gemm_kernel<<<dim3((ODIM / 128) * (MROWS / 128)), 256, 0, stream>>>(
      xbf, wbf, pst, bias2, out);
}